// Round 1
// baseline (83.697 us; speedup 1.0000x reference)
//
#include <hip/hip_runtime.h>
#include <hip/hip_bf16.h>
#include <stdint.h>

#define NPTS 131072

typedef __attribute__((ext_vector_type(8))) short bf16x8;
typedef __attribute__((ext_vector_type(4))) float f32x4;
typedef __attribute__((ext_vector_type(8))) unsigned short u16x8;

__device__ inline unsigned short f32_to_bf16(float f) {
    union { float f; uint32_t u; } v; v.f = f;
    uint32_t u = v.u;
    return (unsigned short)((u + 0x7FFFu + ((u >> 16) & 1u)) >> 16);
}

// Kernel 1: x (8,64,256,256) f32 NCHW -> xt (8,256,256,64) bf16 NHWC
__global__ __launch_bounds__(256) void k_transpose(const float* __restrict__ x,
                                                   unsigned short* __restrict__ xt) {
    __shared__ float tile[64][65];  // +1 pad breaks bank aliasing
    int bid = blockIdx.x;
    int batch = bid >> 10;
    int pix0 = (bid & 1023) << 6;
    int t = threadIdx.x;
    const float* xb = x + (size_t)batch * 64 * 65536;

    int c0 = t >> 4;            // 0..15
    int px = (t & 15) << 2;     // 0..60 step 4
#pragma unroll
    for (int i = 0; i < 4; ++i) {
        int c = c0 + i * 16;
        float4 v = *(const float4*)(xb + (size_t)c * 65536 + pix0 + px);
        tile[c][px + 0] = v.x; tile[c][px + 1] = v.y;
        tile[c][px + 2] = v.z; tile[c][px + 3] = v.w;
    }
    __syncthreads();

    int c8 = (t & 7) << 3;      // 0..56 step 8
    int pp = t >> 3;            // 0..31
#pragma unroll
    for (int h = 0; h < 2; ++h) {
        int pix = pp + h * 32;
        u16x8 o;
#pragma unroll
        for (int i = 0; i < 8; ++i) o[i] = f32_to_bf16(tile[c8 + i][pix]);
        *(u16x8*)(xt + ((size_t)(batch * 65536 + pix0 + pix) * 64 + c8)) = o;
    }
}

// Kernel 2: weight (64,64,3,3) f32 -> Wtn[c2][q*64+c] bf16 (q = dy*3+dx)
__global__ __launch_bounds__(256) void k_wreorder(const float* __restrict__ w,
                                                  unsigned short* __restrict__ wtn) {
    int o = blockIdx.x * 256 + threadIdx.x;
    if (o >= 64 * 576) return;
    int c2 = o / 576;
    int rem = o - c2 * 576;
    int q = rem >> 6;
    int c = rem & 63;
    wtn[o] = f32_to_bf16(w[c2 * 576 + c * 9 + q]);
}

// Kernel 3: gather + GEMM. 64 points/block, 256 threads (4 waves),
// wave w owns output channels [16w,16w+16). K=576 chunked by stencil row.
__global__ __launch_bounds__(256, 3) void k_gather_gemm(
    const unsigned short* __restrict__ xt,
    const unsigned short* __restrict__ wtn,
    const int* __restrict__ indices,
    const float* __restrict__ bias,
    float* __restrict__ out) {
    __shared__ unsigned short A[2][64][200];  // 200 = 192 + 8 pad (row 400 B)
    __shared__ int sidx[192];

    int t = threadIdx.x;
    int tile = blockIdx.x;
    int w = t >> 6;
    int l = t & 63;

    // B fragments: 18 K-tiles, lane l holds Wtn[16w+(l&15)][kt*32+(l>>4)*8 ..+7]
    bf16x8 bfrag[18];
    const unsigned short* wrow = wtn + (size_t)(w * 16 + (l & 15)) * 576 + ((l >> 4) << 3);
#pragma unroll
    for (int kt = 0; kt < 18; ++kt)
        bfrag[kt] = *(const bf16x8*)(wrow + kt * 32);

    if (t < 192) sidx[t] = indices[tile * 192 + t];
    __syncthreads();

    auto stage = [&](int ch, int buf) {
        // 64 points x 3 pixels = 192 segments, 8 lanes x 16 B each -> 6 iters
#pragma unroll
        for (int it = 0; it < 6; ++it) {
            int s = it * 32 + (t >> 3);  // 0..191
            int p = s / 3;
            int qq = s - p * 3;
            int b  = sidx[p * 3 + 0];
            int yy = sidx[p * 3 + 1] + ch - 1;
            int xx = sidx[p * 3 + 2] + qq - 1;
            u16x8 v = (u16x8)0;
            if ((unsigned)yy < 256u && (unsigned)xx < 256u) {
                size_t pix = (size_t)(b << 16) + (yy << 8) + xx;
                v = *(const u16x8*)(xt + pix * 64 + ((t & 7) << 3));
            }
            *(u16x8*)(&A[buf][p][qq * 64 + ((t & 7) << 3)]) = v;
        }
    };

    f32x4 acc[4];
#pragma unroll
    for (int mm = 0; mm < 4; ++mm) acc[mm] = (f32x4)0.0f;

    stage(0, 0);
#pragma unroll
    for (int ch = 0; ch < 3; ++ch) {
        __syncthreads();  // staged chunk visible; prev compute done
        if (ch < 2) stage(ch + 1, (ch + 1) & 1);
        int buf = ch & 1;
#pragma unroll
        for (int ktl = 0; ktl < 6; ++ktl) {
#pragma unroll
            for (int mm = 0; mm < 4; ++mm) {
                bf16x8 a = *(const bf16x8*)(&A[buf][mm * 16 + (l & 15)][ktl * 32 + ((l >> 4) << 3)]);
                acc[mm] = __builtin_amdgcn_mfma_f32_16x16x32_bf16(a, bfrag[ch * 6 + ktl], acc[mm], 0, 0, 0);
            }
        }
    }

    // Epilogue: D frag col = l&15 (n), row = (l>>4)*4 + r
    int col = w * 16 + (l & 15);
    float bv = bias[col];
    int row_base = tile * 64 + ((l >> 4) << 2);
#pragma unroll
    for (int mm = 0; mm < 4; ++mm) {
#pragma unroll
        for (int r = 0; r < 4; ++r) {
            out[(size_t)(row_base + mm * 16 + r) * 64 + col] = acc[mm][r] + bv;
        }
    }
}

// Fallback if workspace too small: naive direct conv (correct, slow)
__global__ void k_naive(const float* __restrict__ x, const int* __restrict__ idx,
                        const float* __restrict__ w, const float* __restrict__ bias,
                        float* __restrict__ out) {
    int i = blockIdx.x * 256 + threadIdx.x;
    if (i >= NPTS * 64) return;
    int p = i >> 6, c2 = i & 63;
    int b = idx[p * 3], yi = idx[p * 3 + 1], xi = idx[p * 3 + 2];
    float acc = bias[c2];
    for (int c = 0; c < 64; ++c) {
        const float* xp = x + ((size_t)(b * 64 + c) << 16);
        const float* wp = w + (c2 * 64 + c) * 9;
        for (int dy = 0; dy < 3; ++dy) {
            int yy = yi + dy - 1;
            if ((unsigned)yy >= 256u) continue;
            for (int dx = 0; dx < 3; ++dx) {
                int xx = xi + dx - 1;
                if ((unsigned)xx >= 256u) continue;
                acc += xp[(yy << 8) + xx] * wp[dy * 3 + dx];
            }
        }
    }
    out[i] = acc;
}

extern "C" void kernel_launch(void* const* d_in, const int* in_sizes, int n_in,
                              void* d_out, int out_size, void* d_ws, size_t ws_size,
                              hipStream_t stream) {
    const float* x       = (const float*)d_in[0];
    const int*   indices = (const int*)d_in[1];
    const float* weight  = (const float*)d_in[2];
    const float* bias    = (const float*)d_in[3];
    float* out = (float*)d_out;

    size_t xt_bytes = (size_t)8 * 65536 * 64 * 2;   // 67,108,864
    size_t need = xt_bytes + (size_t)64 * 576 * 2;  // + 73,728
    if (ws_size < need) {
        k_naive<<<(NPTS * 64 + 255) / 256, 256, 0, stream>>>(x, indices, weight, bias, out);
        return;
    }
    unsigned short* xt  = (unsigned short*)d_ws;
    unsigned short* wtn = (unsigned short*)((char*)d_ws + xt_bytes);

    k_transpose<<<8192, 256, 0, stream>>>(x, xt);
    k_wreorder<<<(64 * 576 + 255) / 256, 256, 0, stream>>>(weight, wtn);
    k_gather_gemm<<<2048, 256, 0, stream>>>(xt, wtn, indices, bias, out);
}

// Round 2
// 67.173 us; speedup vs baseline: 1.2460x; 1.2460x over previous
//
#include <hip/hip_runtime.h>
#include <hip/hip_bf16.h>
#include <stdint.h>

#define NPTS 131072

typedef __attribute__((ext_vector_type(8))) short bf16x8;
typedef __attribute__((ext_vector_type(4))) float f32x4;
typedef __attribute__((ext_vector_type(8))) unsigned short u16x8;

__device__ inline unsigned short f32_to_bf16(float f) {
    union { float f; uint32_t u; } v; v.f = f;
    uint32_t u = v.u;
    return (unsigned short)((u + 0x7FFFu + ((u >> 16) & 1u)) >> 16);
}

// Kernel 1: x (8,64,256,256) f32 NCHW -> xt (8,256,256,64) bf16 NHWC
__global__ __launch_bounds__(256) void k_transpose(const float* __restrict__ x,
                                                   unsigned short* __restrict__ xt) {
    __shared__ float tile[64][65];  // +1 pad breaks bank aliasing
    int bid = blockIdx.x;
    int batch = bid >> 10;
    int pix0 = (bid & 1023) << 6;
    int t = threadIdx.x;
    const float* xb = x + (size_t)batch * 64 * 65536;

    int c0 = t >> 4;            // 0..15
    int px = (t & 15) << 2;     // 0..60 step 4
#pragma unroll
    for (int i = 0; i < 4; ++i) {
        int c = c0 + i * 16;
        float4 v = *(const float4*)(xb + (size_t)c * 65536 + pix0 + px);
        tile[c][px + 0] = v.x; tile[c][px + 1] = v.y;
        tile[c][px + 2] = v.z; tile[c][px + 3] = v.w;
    }
    __syncthreads();

    int c8 = (t & 7) << 3;      // 0..56 step 8
    int pp = t >> 3;            // 0..31
#pragma unroll
    for (int h = 0; h < 2; ++h) {
        int pix = pp + h * 32;
        u16x8 o;
#pragma unroll
        for (int i = 0; i < 8; ++i) o[i] = f32_to_bf16(tile[c8 + i][pix]);
        *(u16x8*)(xt + ((size_t)(batch * 65536 + pix0 + pix) * 64 + c8)) = o;
    }
}

// Kernel 2: weight (64,64,3,3) f32 -> Wtn[c2][q*64+c] bf16 (q = dy*3+dx)
__global__ __launch_bounds__(256) void k_wreorder(const float* __restrict__ w,
                                                  unsigned short* __restrict__ wtn) {
    int o = blockIdx.x * 256 + threadIdx.x;
    if (o >= 64 * 576) return;
    int c2 = o / 576;
    int rem = o - c2 * 576;
    int q = rem >> 6;
    int c = rem & 63;
    wtn[o] = f32_to_bf16(w[c2 * 576 + c * 9 + q]);
}

// Kernel 3: gather + GEMM, wave-owns-points layout.
// 512 threads = 8 waves; each wave owns 16 points x all 64 output channels.
// A-fragments gathered DIRECTLY global->registers (each lane: one point's 9
// stencil pixels, addresses computed once). Weights staged in LDS (padded).
__global__ __launch_bounds__(512, 4) void k_gather_gemm(
    const unsigned short* __restrict__ xt,
    const unsigned short* __restrict__ wtn,
    const int* __restrict__ indices,
    const float* __restrict__ bias,
    float* __restrict__ out) {
    __shared__ unsigned short wlds[64 * 584];  // [c2][584]; 584 pad -> 4-bank lane stride

    int t = threadIdx.x;
    int tile = blockIdx.x;
    int w = t >> 6;     // wave 0..7
    int l = t & 63;
    int lo = l & 15;
    int hi = l >> 4;

    // Stage weights: 64*576 bf16 = 4608 16B-chunks, 9 per thread
#pragma unroll
    for (int i = 0; i < 9; ++i) {
        int m = t + i * 512;
        int row = m / 72;
        int col = (m - row * 72) * 8;
        *(u16x8*)(&wlds[row * 584 + col]) = *(const u16x8*)(wtn + row * 576 + col);
    }

    // This lane's point (wave owns points [tile*128 + w*16, +16))
    int pt = tile * 128 + w * 16 + lo;
    int b  = indices[pt * 3 + 0];
    int yi = indices[pt * 3 + 1];
    int xi = indices[pt * 3 + 2];

    // 9 stencil pixel byte-offsets into xt (+ lane's 16B sub-chunk), validity
    uint32_t off[9];
    bool val[9];
#pragma unroll
    for (int q = 0; q < 9; ++q) {
        int yy = yi + (q / 3) - 1;
        int xx = xi + (q % 3) - 1;
        bool v = ((unsigned)yy < 256u) & ((unsigned)xx < 256u);
        uint32_t pix = ((uint32_t)b << 16) + ((uint32_t)(yy & 255) << 8) + (uint32_t)(xx & 255);
        val[q] = v;
        off[q] = (v ? pix * 128u : 0u) + (uint32_t)(hi << 4);
    }

    auto lda = [&](int q, int half) -> bf16x8 {
        const u16x8* p = (const u16x8*)((const char*)xt + off[q] + half * 64);
        u16x8 d = *p;
        u16x8 z = {};
        return (bf16x8)(val[q] ? d : z);
    };

    f32x4 acc[4];
#pragma unroll
    for (int nn = 0; nn < 4; ++nn) acc[nn] = (f32x4)0.0f;

    __syncthreads();  // wlds ready

    bf16x8 a0 = lda(0, 0), a1 = lda(0, 1);
#pragma unroll
    for (int q = 0; q < 9; ++q) {
        bf16x8 n0, n1;
        if (q < 8) { n0 = lda(q + 1, 0); n1 = lda(q + 1, 1); }
        // B frag: channel = nn*16+lo, k = q*64 + half*32 + hi*8
#pragma unroll
        for (int nn = 0; nn < 4; ++nn) {
            bf16x8 b0 = *(const bf16x8*)(&wlds[(nn * 16 + lo) * 584 + q * 64 + (hi << 3)]);
            acc[nn] = __builtin_amdgcn_mfma_f32_16x16x32_bf16(a0, b0, acc[nn], 0, 0, 0);
        }
#pragma unroll
        for (int nn = 0; nn < 4; ++nn) {
            bf16x8 b1 = *(const bf16x8*)(&wlds[(nn * 16 + lo) * 584 + q * 64 + 32 + (hi << 3)]);
            acc[nn] = __builtin_amdgcn_mfma_f32_16x16x32_bf16(a1, b1, acc[nn], 0, 0, 0);
        }
        a0 = n0; a1 = n1;
    }

    // Epilogue: D col = lo (channel within nn-tile), row = hi*4 + r (point)
    int row_base = tile * 128 + w * 16 + (hi << 2);
#pragma unroll
    for (int nn = 0; nn < 4; ++nn) {
        float bv = bias[nn * 16 + lo];
#pragma unroll
        for (int r = 0; r < 4; ++r) {
            out[(size_t)(row_base + r) * 64 + nn * 16 + lo] = acc[nn][r] + bv;
        }
        (void)bv;
    }
}

// Fallback if workspace too small: naive direct conv (correct, slow)
__global__ void k_naive(const float* __restrict__ x, const int* __restrict__ idx,
                        const float* __restrict__ w, const float* __restrict__ bias,
                        float* __restrict__ out) {
    int i = blockIdx.x * 256 + threadIdx.x;
    if (i >= NPTS * 64) return;
    int p = i >> 6, c2 = i & 63;
    int b = idx[p * 3], yi = idx[p * 3 + 1], xi = idx[p * 3 + 2];
    float acc = bias[c2];
    for (int c = 0; c < 64; ++c) {
        const float* xp = x + ((size_t)(b * 64 + c) << 16);
        const float* wp = w + (c2 * 64 + c) * 9;
        for (int dy = 0; dy < 3; ++dy) {
            int yy = yi + dy - 1;
            if ((unsigned)yy >= 256u) continue;
            for (int dx = 0; dx < 3; ++dx) {
                int xx = xi + dx - 1;
                if ((unsigned)xx >= 256u) continue;
                acc += xp[(yy << 8) + xx] * wp[dy * 3 + dx];
            }
        }
    }
    out[i] = acc;
}

extern "C" void kernel_launch(void* const* d_in, const int* in_sizes, int n_in,
                              void* d_out, int out_size, void* d_ws, size_t ws_size,
                              hipStream_t stream) {
    const float* x       = (const float*)d_in[0];
    const int*   indices = (const int*)d_in[1];
    const float* weight  = (const float*)d_in[2];
    const float* bias    = (const float*)d_in[3];
    float* out = (float*)d_out;

    size_t xt_bytes = (size_t)8 * 65536 * 64 * 2;   // 67,108,864
    size_t need = xt_bytes + (size_t)64 * 576 * 2;  // + 73,728
    if (ws_size < need) {
        k_naive<<<(NPTS * 64 + 255) / 256, 256, 0, stream>>>(x, indices, weight, bias, out);
        return;
    }
    unsigned short* xt  = (unsigned short*)d_ws;
    unsigned short* wtn = (unsigned short*)((char*)d_ws + xt_bytes);

    k_transpose<<<8192, 256, 0, stream>>>(x, xt);
    k_wreorder<<<(64 * 576 + 255) / 256, 256, 0, stream>>>(weight, wtn);
    k_gather_gemm<<<NPTS / 128, 512, 0, stream>>>(xt, wtn, indices, bias, out);
}

// Round 3
// 64.090 us; speedup vs baseline: 1.3059x; 1.0481x over previous
//
#include <hip/hip_runtime.h>
#include <hip/hip_bf16.h>
#include <stdint.h>

#define NPTS 131072

typedef __attribute__((ext_vector_type(8))) short bf16x8;
typedef __attribute__((ext_vector_type(4))) float f32x4;
typedef __attribute__((ext_vector_type(8))) unsigned short u16x8;

__device__ inline unsigned short f32_to_bf16(float f) {
    union { float f; uint32_t u; } v; v.f = f;
    uint32_t u = v.u;
    return (unsigned short)((u + 0x7FFFu + ((u >> 16) & 1u)) >> 16);
}

// Kernel 1 (fused): blocks [0,8192): x NCHW f32 -> xt NHWC bf16.
// Blocks [8192, 8210): weight (64,64,3,3) f32 -> fragment-ordered wfrag bf16,
//                      plus zero the 128 B OOB pad at the end of xt.
// wfrag chunk ci = q*8 + half*4 + nn (1 KB each): lane l, elem e holds
//   w[c2=nn*16+(l&15)][cin=half*32+(l>>4)*8+e][q]   (q = dy*3+dx)
__global__ __launch_bounds__(256) void k_transpose(const float* __restrict__ x,
                                                   unsigned short* __restrict__ xt,
                                                   const float* __restrict__ w,
                                                   unsigned short* __restrict__ wfrag) {
    if (blockIdx.x >= 8192) {
        int tid = (blockIdx.x - 8192) * 256 + threadIdx.x;  // 0..4607
        if (tid < 4608) {
            int ci = tid >> 6;          // 0..71
            int l  = tid & 63;
            int q    = ci >> 3;
            int half = (ci >> 2) & 1;
            int nn   = ci & 3;
            int c2   = nn * 16 + (l & 15);
            int cin0 = half * 32 + ((l >> 4) << 3);
            u16x8 o;
#pragma unroll
            for (int e = 0; e < 8; ++e)
                o[e] = f32_to_bf16(w[c2 * 576 + (cin0 + e) * 9 + q]);
            *(u16x8*)(wfrag + tid * 8) = o;
        }
        if (blockIdx.x == 8192 && threadIdx.x < 8) {
            u16x8 z = {};
            *(u16x8*)(xt + (size_t)8 * 65536 * 64 + threadIdx.x * 8) = z;
        }
        return;
    }

    __shared__ float tile[64][65];
    int bid = blockIdx.x;
    int batch = bid >> 10;
    int pix0 = (bid & 1023) << 6;
    int t = threadIdx.x;
    const float* xb = x + (size_t)batch * 64 * 65536;

    int c0 = t >> 4;
    int px = (t & 15) << 2;
#pragma unroll
    for (int i = 0; i < 4; ++i) {
        int c = c0 + i * 16;
        float4 v = *(const float4*)(xb + (size_t)c * 65536 + pix0 + px);
        tile[c][px + 0] = v.x; tile[c][px + 1] = v.y;
        tile[c][px + 2] = v.z; tile[c][px + 3] = v.w;
    }
    __syncthreads();

    int c8 = (t & 7) << 3;
    int pp = t >> 3;
#pragma unroll
    for (int h = 0; h < 2; ++h) {
        int pix = pp + h * 32;
        u16x8 o;
#pragma unroll
        for (int i = 0; i < 8; ++i) o[i] = f32_to_bf16(tile[c8 + i][pix]);
        *(u16x8*)(xt + ((size_t)(batch * 65536 + pix0 + pix) * 64 + c8)) = o;
    }
}

// Kernel 3: gather + GEMM. 512 threads = 8 waves; each wave owns 32 points
// (two 16-row M-tiles sharing every B-fragment). A gathered global->regs with
// 1-pixel prefetch; OOB pixels read the zero pad (no per-load selects).
// Weights in LDS, fragment-ordered -> lane-linear ds_read_b128, zero addr VALU.
__global__ __launch_bounds__(512, 4) void k_gather_gemm(
    const unsigned short* __restrict__ xt,
    const unsigned short* __restrict__ wfrag,
    const int* __restrict__ indices,
    const float* __restrict__ bias,
    float* __restrict__ out) {
    __shared__ unsigned short wlds[72 * 512];  // 73728 B

    int t = threadIdx.x;
    int w = t >> 6;
    int l = t & 63;
    int lo = l & 15;
    int hi = l >> 4;

    // Stage weights: 4608 16B-chunks, 9 per thread, fully coalesced
#pragma unroll
    for (int i = 0; i < 9; ++i) {
        int m = t + i * 512;
        *(u16x8*)(&wlds[m * 8]) = *(const u16x8*)(wfrag + m * 8);
    }

    // Wave owns points [p0, p0+32); lane handles points p0+lo (tile 0), p0+16+lo (tile 1)
    int p0 = blockIdx.x * 256 + w * 32;
    int pA = p0 + lo, pB = p0 + 16 + lo;
    int bA = indices[pA * 3], yA = indices[pA * 3 + 1], xA = indices[pA * 3 + 2];
    int bB = indices[pB * 3], yB = indices[pB * 3 + 1], xB = indices[pB * 3 + 2];

    const uint32_t PADOFF = (uint32_t)8 * 65536 * 128;  // byte offset of zero pad
    uint32_t sub = (uint32_t)(hi << 4);

    auto offq = [&](int b, int y, int x, int q) -> uint32_t {
        int yy = y + (q / 3) - 1;
        int xx = x + (q % 3) - 1;
        bool v = ((unsigned)yy < 256u) & ((unsigned)xx < 256u);
        uint32_t pix = ((uint32_t)b << 16) + ((uint32_t)(yy & 255) << 8) + (uint32_t)(xx & 255);
        return (v ? pix * 128u : PADOFF) + sub;
    };
    auto lda = [&](uint32_t o) -> bf16x8 {
        return (bf16x8)(*(const u16x8*)((const char*)xt + o));
    };

    f32x4 acc[2][4];
#pragma unroll
    for (int m = 0; m < 2; ++m)
#pragma unroll
        for (int nn = 0; nn < 4; ++nn) acc[m][nn] = (f32x4)0.0f;

    __syncthreads();  // wlds ready

    uint32_t oA = offq(bA, yA, xA, 0), oB = offq(bB, yB, xB, 0);
    bf16x8 a00 = lda(oA), a01 = lda(oA + 64);   // tile0 half0/half1
    bf16x8 a10 = lda(oB), a11 = lda(oB + 64);   // tile1

#pragma unroll
    for (int q = 0; q < 9; ++q) {
        bf16x8 n00, n01, n10, n11;
        if (q < 8) {
            uint32_t nA = offq(bA, yA, xA, q + 1), nB = offq(bB, yB, xB, q + 1);
            n00 = lda(nA); n01 = lda(nA + 64);
            n10 = lda(nB); n11 = lda(nB + 64);
        }
        const unsigned short* base = &wlds[q * 4096];  // q's 8 chunks (u16 idx)
#pragma unroll
        for (int nn = 0; nn < 4; ++nn) {
            bf16x8 b0 = *(const bf16x8*)(base + nn * 512 + l * 8);          // half0
            acc[0][nn] = __builtin_amdgcn_mfma_f32_16x16x32_bf16(a00, b0, acc[0][nn], 0, 0, 0);
            acc[1][nn] = __builtin_amdgcn_mfma_f32_16x16x32_bf16(a10, b0, acc[1][nn], 0, 0, 0);
        }
#pragma unroll
        for (int nn = 0; nn < 4; ++nn) {
            bf16x8 b1 = *(const bf16x8*)(base + 2048 + nn * 512 + l * 8);   // half1
            acc[0][nn] = __builtin_amdgcn_mfma_f32_16x16x32_bf16(a01, b1, acc[0][nn], 0, 0, 0);
            acc[1][nn] = __builtin_amdgcn_mfma_f32_16x16x32_bf16(a11, b1, acc[1][nn], 0, 0, 0);
        }
        if (q < 8) { a00 = n00; a01 = n01; a10 = n10; a11 = n11; }
    }

    // Epilogue: D col = lo (channel within nn-tile), row = hi*4 + r
    int rbase = blockIdx.x * 256 + w * 32 + (hi << 2);
#pragma unroll
    for (int nn = 0; nn < 4; ++nn) {
        float bv = bias[nn * 16 + lo];
#pragma unroll
        for (int m = 0; m < 2; ++m) {
#pragma unroll
            for (int r = 0; r < 4; ++r) {
                out[(size_t)(rbase + m * 16 + r) * 64 + nn * 16 + lo] = acc[m][nn][r] + bv;
            }
        }
    }
}

// Fallback if workspace too small: naive direct conv (correct, slow)
__global__ void k_naive(const float* __restrict__ x, const int* __restrict__ idx,
                        const float* __restrict__ w, const float* __restrict__ bias,
                        float* __restrict__ out) {
    int i = blockIdx.x * 256 + threadIdx.x;
    if (i >= NPTS * 64) return;
    int p = i >> 6, c2 = i & 63;
    int b = idx[p * 3], yi = idx[p * 3 + 1], xi = idx[p * 3 + 2];
    float acc = bias[c2];
    for (int c = 0; c < 64; ++c) {
        const float* xp = x + ((size_t)(b * 64 + c) << 16);
        const float* wp = w + (c2 * 64 + c) * 9;
        for (int dy = 0; dy < 3; ++dy) {
            int yy = yi + dy - 1;
            if ((unsigned)yy >= 256u) continue;
            for (int dx = 0; dx < 3; ++dx) {
                int xx = xi + dx - 1;
                if ((unsigned)xx >= 256u) continue;
                acc += xp[(yy << 8) + xx] * wp[dy * 3 + dx];
            }
        }
    }
    out[i] = acc;
}

extern "C" void kernel_launch(void* const* d_in, const int* in_sizes, int n_in,
                              void* d_out, int out_size, void* d_ws, size_t ws_size,
                              hipStream_t stream) {
    const float* x       = (const float*)d_in[0];
    const int*   indices = (const int*)d_in[1];
    const float* weight  = (const float*)d_in[2];
    const float* bias    = (const float*)d_in[3];
    float* out = (float*)d_out;

    size_t xt_bytes = (size_t)8 * 65536 * 64 * 2 + 128;   // incl. 128 B zero pad
    size_t need = xt_bytes + (size_t)72 * 1024;           // + wfrag
    if (ws_size < need) {
        k_naive<<<(NPTS * 64 + 255) / 256, 256, 0, stream>>>(x, indices, weight, bias, out);
        return;
    }
    unsigned short* xt    = (unsigned short*)d_ws;
    unsigned short* wfrag = (unsigned short*)((char*)d_ws + xt_bytes);

    k_transpose<<<8192 + 18, 256, 0, stream>>>(x, xt, weight, wfrag);
    k_gather_gemm<<<NPTS / 256, 512, 0, stream>>>(xt, wfrag, indices, bias, out);
}